// Round 2
// baseline (337.929 us; speedup 1.0000x reference)
//
#include <hip/hip_runtime.h>

#define NK 19

// Hexagonal stencil offsets for KS=2, exact order of the reference (center first).
__constant__ int c_ox[NK] = {0, 1,1,0,-1,-1,0, 2,2,2,1,0,-1,-2,-2,-2,-1,0,1};
__constant__ int c_oy[NK] = {0, 1,0,-1,-1,0,1, 2,1,0,-1,-2,-2,-2,-1,0,1,2,2};

#define C0F 0.28209479177387814f   // C0
#define C1F 0.4886025119029199f    // C1
#define IS3 0.5773502691896258f    // 1/sqrt(3)
#define IS2 0.7071067811865476f    // 1/sqrt(2)
#define ASC 0.040555354f           // 1/sqrt(2*19*16)
#define AVC 0.033113308f           // 1/sqrt(3*19*16)

// r == 0 path: out_s[w] = ASC * ( C0*sum s*w000 + (1/sqrt3)*sum (v.sh)*w110 )
__device__ inline void do_s(const float* __restrict__ feat, int n, int x, int y,
                            const float* __restrict__ w000, const float* __restrict__ w110,
                            float sh0, float sh1, float sh2,
                            float* __restrict__ o)
{
    float acc[16];
#pragma unroll
    for (int w = 0; w < 16; ++w) acc[w] = 0.0f;
    for (int k = 0; k < NK; ++k) {
        const int xx = (x + c_ox[k]) & 127;
        const int yy = (y + c_oy[k]) & 127;
        const float* fb = feat + ((((n << 7) + xx) << 7) + yy) * 64;
        const float* wa = w000 + k * 256;
        const float* wb = w110 + k * 256;
#pragma unroll
        for (int u = 0; u < 16; ++u) {
            const float s_val = fb[u];
            const float v0 = fb[16 + 3 * u + 0];
            const float v1 = fb[16 + 3 * u + 1];
            const float v2 = fb[16 + 3 * u + 2];
            const float sA = C0F * s_val;
            const float tB = IS3 * (v0 * sh0 + v1 * sh1 + v2 * sh2);
#pragma unroll
            for (int w = 0; w < 16; ++w) {
                acc[w] = fmaf(sA, wa[u * 16 + w], acc[w]);
                acc[w] = fmaf(tB, wb[u * 16 + w], acc[w]);
            }
        }
    }
#pragma unroll
    for (int w = 0; w < 16; ++w) o[w] = ASC * acc[w];
}

// r == 1..3 path: out_v[w][I] = AVC * ( s*shI*w011 + C0*vI*w101 + (1/sqrt2)*(vJ*shL - vL*shJ)*w111 )
template <int I>
__device__ inline void do_v(const float* __restrict__ feat, int n, int x, int y,
                            const float* __restrict__ w011, const float* __restrict__ w101,
                            const float* __restrict__ w111,
                            float sh0, float sh1, float sh2,
                            float* __restrict__ o)
{
    constexpr int J = (I + 1) % 3;
    constexpr int L = (I + 2) % 3;
    const float shI = (I == 0) ? sh0 : (I == 1) ? sh1 : sh2;
    const float shJ = (J == 0) ? sh0 : (J == 1) ? sh1 : sh2;
    const float shL = (L == 0) ? sh0 : (L == 1) ? sh1 : sh2;
    float acc[16];
#pragma unroll
    for (int w = 0; w < 16; ++w) acc[w] = 0.0f;
    for (int k = 0; k < NK; ++k) {
        const int xx = (x + c_ox[k]) & 127;
        const int yy = (y + c_oy[k]) & 127;
        const float* fb = feat + ((((n << 7) + xx) << 7) + yy) * 64;
        const float* wa = w011 + k * 256;
        const float* wb = w101 + k * 256;
        const float* wc = w111 + k * 256;
#pragma unroll
        for (int u = 0; u < 16; ++u) {
            const float s_val = fb[u];
            const float vI = fb[16 + 3 * u + I];
            const float vJ = fb[16 + 3 * u + J];
            const float vL = fb[16 + 3 * u + L];
            const float a1 = s_val * shI;                      // scalar * sh1_I
            const float a2 = C0F * vI;                         // C0 * v_I
            const float a3 = IS2 * (vJ * shL - vL * shJ);      // (v x sh1)_I / sqrt2
#pragma unroll
            for (int w = 0; w < 16; ++w) {
                acc[w] = fmaf(a1, wa[u * 16 + w], acc[w]);
                acc[w] = fmaf(a2, wb[u * 16 + w], acc[w]);
                acc[w] = fmaf(a3, wc[u * 16 + w], acc[w]);
            }
        }
    }
#pragma unroll
    for (int w = 0; w < 16; ++w) o[3 * w] = AVC * acc[w];
}

__global__ __launch_bounds__(256) void spinconv_kernel(
    const float* __restrict__ feat, const float* __restrict__ spin,
    const float* __restrict__ w000, const float* __restrict__ w011,
    const float* __restrict__ w101, const float* __restrict__ w110,
    const float* __restrict__ w111, float* __restrict__ out)
{
    const int p = blockIdx.x * 64 + threadIdx.x;   // pixel index over N*Lx*Ly
    const int r = threadIdx.y;                     // wave-uniform role: 0 = out_s, 1..3 = out_v[:,r-1]
    const int n = p >> 14;
    const int x = (p >> 7) & 127;
    const int y = p & 127;
    const float sp0 = spin[3 * p + 0];
    const float sp1 = spin[3 * p + 1];
    const float sp2 = spin[3 * p + 2];
    // sh1 = C1 * spin[..., [1,2,0]]
    const float sh0 = C1F * sp1;
    const float sh1 = C1F * sp2;
    const float sh2 = C1F * sp0;
    float* o = out + (size_t)p * 64;
    if (r == 0)      do_s(feat, n, x, y, w000, w110, sh0, sh1, sh2, o);
    else if (r == 1) do_v<0>(feat, n, x, y, w011, w101, w111, sh0, sh1, sh2, o + 16);
    else if (r == 2) do_v<1>(feat, n, x, y, w011, w101, w111, sh0, sh1, sh2, o + 17);
    else             do_v<2>(feat, n, x, y, w011, w101, w111, sh0, sh1, sh2, o + 18);
}

extern "C" void kernel_launch(void* const* d_in, const int* in_sizes, int n_in,
                              void* d_out, int out_size, void* d_ws, size_t ws_size,
                              hipStream_t stream) {
    const float* feat = (const float*)d_in[0];
    const float* spin = (const float*)d_in[1];
    const float* w000 = (const float*)d_in[2];
    const float* w011 = (const float*)d_in[3];
    const float* w101 = (const float*)d_in[4];
    const float* w110 = (const float*)d_in[5];
    const float* w111 = (const float*)d_in[6];
    float* out = (float*)d_out;

    const int npix = 4 * 128 * 128;           // 65536
    dim3 grid(npix / 64);                     // 1024 blocks
    dim3 block(64, 4);                        // x: pixels, y: role r (wave-uniform)
    hipLaunchKernelGGL(spinconv_kernel, grid, block, 0, stream,
                       feat, spin, w000, w011, w101, w110, w111, out);
}

// Round 3
// 95.479 us; speedup vs baseline: 3.5393x; 3.5393x over previous
//
#include <hip/hip_runtime.h>

typedef __attribute__((ext_vector_type(8))) short short8;
typedef __attribute__((ext_vector_type(4))) float f32x4;

#define C0F 0.28209479177387814f
#define C1F 0.4886025119029199f
#define IS3 0.5773502691896258f
#define IS2 0.7071067811865476f
#define ASC 0.040555354f   // 1/sqrt(2*19*16)
#define AVC 0.033113308f   // 1/sqrt(3*19*16)

#define FEAT_STRIDE 144        // bytes per staged pixel (64ch bf16 = 128 B + 16 pad -> 2-way banks)
#define W_LDS_BASE 20736       // 144 slots * 144 B
#define W_M_STRIDE 10240       // 20 taps * 16 w * 16 u * 2 B
#define LDS_TOTAL (20736 + 5 * 10240)   // 71936 B

// staged-slot delta per tap: ox*12 + oy (hex stencil order, tap 19 = zero-pad -> any valid slot)
__constant__ int c_doff[20] = {0, 13, 12, -1, -13, -12, 1,
                               26, 25, 24, 11, -2, -14, -26, -25, -24, -11, 2, 14, 0};

__device__ inline unsigned short f32_bf16(float x) {
    unsigned int u = __float_as_uint(x);
    return (unsigned short)((u + 0x7FFF + ((u >> 16) & 1)) >> 16);
}

// ---- prepass: convert 5 weight tensors f32 [19][u16][w16] -> bf16 ws [m][tap20][w16][u16]
__global__ __launch_bounds__(256) void wprep_kernel(
    const float* __restrict__ w000, const float* __restrict__ w011,
    const float* __restrict__ w101, const float* __restrict__ w110,
    const float* __restrict__ w111, unsigned short* __restrict__ wout)
{
    int o = blockIdx.x * 256 + threadIdx.x;        // [0, 25600)
    int m = o / 5120;
    int r1 = o - m * 5120;
    int tap = r1 >> 8;
    int r2 = r1 & 255;
    int w = r2 >> 4;
    int u = r2 & 15;
    const float* W = (m == 0) ? w000 : (m == 1) ? w011 : (m == 2) ? w101 : (m == 3) ? w110 : w111;
    float val = (tap < 19) ? W[tap * 256 + u * 16 + w] : 0.0f;
    wout[o] = f32_bf16(val);
}

// ---- main: implicit-GEMM stencil conv via mfma_f32_16x16x32_bf16
__global__ __launch_bounds__(256) void spinconv_mfma(
    const float* __restrict__ feat, const float* __restrict__ spin,
    const unsigned short* __restrict__ wbf, float* __restrict__ out)
{
    extern __shared__ char smem[];
    const int tid = threadIdx.x;
    const int b = blockIdx.x;
    const int n = b >> 8;
    const int X0 = ((b >> 4) & 15) << 3;
    const int Y0 = (b & 15) << 3;

    // stage weights: 51200 B linear copy (bf16, already in frag-friendly layout)
    for (int r = 0; r < 13; ++r) {
        int off = r * 4096 + tid * 16;
        if (off < 51200) {
            short8 v = *(const short8*)((const char*)wbf + off);
            *(short8*)(smem + W_LDS_BASE + off) = v;
        }
    }
    // stage feat 12x12 halo tile: coalesced float4 reads, de-interleave to [slot][s16|v0_16|v1_16|v2_16] bf16
    for (int r = 0; r < 9; ++r) {
        int p = (tid >> 4) + (r << 4);             // staged slot 0..143
        int j4 = tid & 15;                         // float4 index within pixel
        int dx = p / 12, dy = p - dx * 12;
        int gx = (X0 - 2 + dx) & 127;
        int gy = (Y0 - 2 + dy) & 127;
        const float4 v = ((const float4*)(feat + ((((n << 7) + gx) << 7) + gy) * 64))[j4];
        char* dstb = smem + p * FEAT_STRIDE;
        float vals[4] = {v.x, v.y, v.z, v.w};
        int ch0 = j4 * 4;
#pragma unroll
        for (int c = 0; c < 4; ++c) {
            int ch = ch0 + c;
            int j = ch - 16;
            int dst = (ch < 16) ? ch : (16 + 16 * (j % 3) + j / 3);
            *(unsigned short*)(dstb + dst * 2) = f32_bf16(vals[c]);
        }
    }
    __syncthreads();

    const int lane = tid & 63;
    const int wave = tid >> 6;
    const int lx = lane & 15;          // A: pixel row; B: w col; D: w col
    const int q = lane >> 4;
    const int u0b = (q & 1) << 4;      // byte offset of 8-u half
    const int taph = q >> 1;           // which tap of the K-step pair
    const int ploc = (wave << 4) + lx; // pixel this lane supplies for A
    const int slot0 = ((ploc >> 3) + 2) * 12 + ((ploc & 7) + 2);
    const char* wlds = smem + W_LDS_BASE;

    f32x4 aS0{0,0,0,0}, aS1{0,0,0,0};
    f32x4 aB0{0,0,0,0}, aB1{0,0,0,0}, aB2{0,0,0,0};
    f32x4 aC0{0,0,0,0}, aC1{0,0,0,0}, aC2{0,0,0,0};
    f32x4 aD0{0,0,0,0}, aD1{0,0,0,0}, aD2{0,0,0,0};

#pragma unroll
    for (int t = 0; t < 10; ++t) {
        const int tap = 2 * t + taph;
        const char* ab = smem + (slot0 + c_doff[tap]) * FEAT_STRIDE + u0b;
        short8 a_s  = *(const short8*)(ab);
        short8 a_v0 = *(const short8*)(ab + 32);
        short8 a_v1 = *(const short8*)(ab + 64);
        short8 a_v2 = *(const short8*)(ab + 96);
        const char* bb = wlds + tap * 512 + lx * 32 + u0b;
        short8 b000 = *(const short8*)(bb);
        short8 b011 = *(const short8*)(bb + 1 * W_M_STRIDE);
        short8 b101 = *(const short8*)(bb + 2 * W_M_STRIDE);
        short8 b110 = *(const short8*)(bb + 3 * W_M_STRIDE);
        short8 b111 = *(const short8*)(bb + 4 * W_M_STRIDE);
        aS0 = __builtin_amdgcn_mfma_f32_16x16x32_bf16(a_s,  b000, aS0, 0, 0, 0);
        aS1 = __builtin_amdgcn_mfma_f32_16x16x32_bf16(a_s,  b011, aS1, 0, 0, 0);
        aB0 = __builtin_amdgcn_mfma_f32_16x16x32_bf16(a_v0, b101, aB0, 0, 0, 0);
        aC0 = __builtin_amdgcn_mfma_f32_16x16x32_bf16(a_v0, b110, aC0, 0, 0, 0);
        aD0 = __builtin_amdgcn_mfma_f32_16x16x32_bf16(a_v0, b111, aD0, 0, 0, 0);
        aB1 = __builtin_amdgcn_mfma_f32_16x16x32_bf16(a_v1, b101, aB1, 0, 0, 0);
        aC1 = __builtin_amdgcn_mfma_f32_16x16x32_bf16(a_v1, b110, aC1, 0, 0, 0);
        aD1 = __builtin_amdgcn_mfma_f32_16x16x32_bf16(a_v1, b111, aD1, 0, 0, 0);
        aB2 = __builtin_amdgcn_mfma_f32_16x16x32_bf16(a_v2, b101, aB2, 0, 0, 0);
        aC2 = __builtin_amdgcn_mfma_f32_16x16x32_bf16(a_v2, b110, aC2, 0, 0, 0);
        aD2 = __builtin_amdgcn_mfma_f32_16x16x32_bf16(a_v2, b111, aD2, 0, 0, 0);
    }

    // epilogue: D row = pixel = q*4+r, col = w = lx
    const int w = lx;
#pragma unroll
    for (int r = 0; r < 4; ++r) {
        const int pl = (wave << 4) + (q << 2) + r;
        const int gx = X0 + (pl >> 3);
        const int gy = Y0 + (pl & 7);
        const int P = (((n << 7) + gx) << 7) + gy;
        const float s0 = C1F * spin[3 * P + 1];   // sh1 = C1*spin[...,[1,2,0]]
        const float s1 = C1F * spin[3 * P + 2];
        const float s2 = C1F * spin[3 * P + 0];
        float* o = out + (size_t)P * 64;
        o[w] = ASC * (C0F * aS0[r] + IS3 * (s0 * aC0[r] + s1 * aC1[r] + s2 * aC2[r]));
        // out_v_i = AVC*( sh_i*A1 + C0*B_i + IS2*(sh_L*D_J - sh_J*D_L) ), (i,J,L) cyclic
        o[16 + 3 * w + 0] = AVC * (s0 * aS1[r] + C0F * aB0[r] + IS2 * (s2 * aD1[r] - s1 * aD2[r]));
        o[16 + 3 * w + 1] = AVC * (s1 * aS1[r] + C0F * aB1[r] + IS2 * (s0 * aD2[r] - s2 * aD0[r]));
        o[16 + 3 * w + 2] = AVC * (s2 * aS1[r] + C0F * aB2[r] + IS2 * (s1 * aD0[r] - s0 * aD1[r]));
    }
}

extern "C" void kernel_launch(void* const* d_in, const int* in_sizes, int n_in,
                              void* d_out, int out_size, void* d_ws, size_t ws_size,
                              hipStream_t stream) {
    const float* feat = (const float*)d_in[0];
    const float* spin = (const float*)d_in[1];
    const float* w000 = (const float*)d_in[2];
    const float* w011 = (const float*)d_in[3];
    const float* w101 = (const float*)d_in[4];
    const float* w110 = (const float*)d_in[5];
    const float* w111 = (const float*)d_in[6];
    float* out = (float*)d_out;
    unsigned short* wbf = (unsigned short*)d_ws;   // 25600 bf16 = 51200 B

    static bool attr_set = false;
    if (!attr_set) {
        (void)hipFuncSetAttribute((const void*)spinconv_mfma,
                                  hipFuncAttributeMaxDynamicSharedMemorySize, LDS_TOTAL);
        attr_set = true;
    }

    hipLaunchKernelGGL(wprep_kernel, dim3(100), dim3(256), 0, stream,
                       w000, w011, w101, w110, w111, wbf);
    hipLaunchKernelGGL(spinconv_mfma, dim3(1024), dim3(256), LDS_TOTAL, stream,
                       feat, spin, wbf, out);
}

// Round 4
// 92.461 us; speedup vs baseline: 3.6548x; 1.0327x over previous
//
#include <hip/hip_runtime.h>

typedef __attribute__((ext_vector_type(8))) short short8;
typedef __attribute__((ext_vector_type(4))) float f32x4;
typedef __attribute__((ext_vector_type(4))) int i32x4;

#define C0F 0.28209479177387814f
#define C1F 0.4886025119029199f
#define IS3 0.5773502691896258f
#define IS2 0.7071067811865476f
#define ASC 0.040555354f   // 1/sqrt(2*19*16)
#define AVC 0.033113308f   // 1/sqrt(3*19*16)

#define WBYTES 51200                    // 5 mats * 20 taps * 256 * 2B, LDS [0, 51200)
#define FLDS   51200                    // feat tile LDS offset
#define LDS_TOTAL (51200 + 18432)       // 69632 B

// staged-slot delta per tap (slot stride 12); tap 19 = zero-weight pad
__constant__ int c_doff[20] = {0, 13, 12, -1, -13, -12, 1,
                               26, 25, 24, 11, -2, -14, -26, -25, -24, -11, 2, 14, 0};

__device__ inline unsigned short f32_bf16(float x) {
    unsigned int u = __float_as_uint(x);
    return (unsigned short)((u + 0x7FFF + ((u >> 16) & 1)) >> 16);
}

#define GLD16(gp, lp) __builtin_amdgcn_global_load_lds( \
    (const __attribute__((address_space(1))) unsigned int*)(gp), \
    (__attribute__((address_space(3))) unsigned int*)(lp), 16, 0, 0)

// ---- prepass: blocks [0,2048) convert feat -> de-interleaved, pre-swizzled bf16 (32 px/block);
//               blocks [2048,2148) convert 5 weight tensors -> bf16 [m][tap20][w16][u16]
__global__ __launch_bounds__(256) void prep_kernel(
    const float* __restrict__ feat,
    const float* __restrict__ w000, const float* __restrict__ w011,
    const float* __restrict__ w101, const float* __restrict__ w110,
    const float* __restrict__ w111, unsigned char* __restrict__ ws)
{
    const int t = threadIdx.x;
    if (blockIdx.x >= 2048) {
        int o = (blockIdx.x - 2048) * 256 + t;          // [0, 25600)
        int m = o / 5120;
        int r1 = o - m * 5120;
        int tap = r1 >> 8;
        int r2 = r1 & 255;
        int w = r2 >> 4;
        int u = r2 & 15;
        const float* W = (m == 0) ? w000 : (m == 1) ? w011 : (m == 2) ? w101 : (m == 3) ? w110 : w111;
        float val = (tap < 19) ? W[tap * 256 + u * 16 + w] : 0.0f;
        ((unsigned short*)ws)[o] = f32_bf16(val);
        return;
    }
    __shared__ float raw[2048];                          // 32 px * 64 ch
    const int P0 = blockIdx.x * 32;
    const float4* src = (const float4*)feat + (size_t)P0 * 16;
    float4 l0 = src[t * 2];
    float4 l1 = src[t * 2 + 1];
    *(float4*)&raw[t * 8] = l0;
    *(float4*)&raw[t * 8 + 4] = l1;
    __syncthreads();
    const int p = t >> 3;                                // local pixel
    const int c = t & 7;                                 // 16B chunk id
    const float* r = &raw[p * 64];
    int ch0, stride;
    if (c < 2) { ch0 = c * 8; stride = 1; }
    else { int i = (c - 2) >> 1, uh = (c - 2) & 1; ch0 = 16 + i + 24 * uh; stride = 3; }
    unsigned int pk[4];
#pragma unroll
    for (int e = 0; e < 4; ++e) {
        unsigned int lo = f32_bf16(r[ch0 + stride * (2 * e)]);
        unsigned int hi = f32_bf16(r[ch0 + stride * (2 * e + 1)]);
        pk[e] = lo | (hi << 16);
    }
    const int PX = P0 + p;
    const int gy = PX & 127, gx = (PX >> 7) & 127;
    const int k = (4 * gx + gy + 2) & 7;                 // == slot%8 for every tile (origins % 8 == 0)
    *(i32x4*)(ws + WBYTES + (size_t)PX * 128 + ((c ^ k) << 4)) = *(const i32x4*)pk;
}

// ---- main: implicit-GEMM stencil conv, global_load_lds staging, swizzled A-reads
__global__ __launch_bounds__(256) void spinconv_mfma(
    const unsigned char* __restrict__ ws, const float* __restrict__ spin,
    float* __restrict__ out)
{
    extern __shared__ char smem[];
    const int tid = threadIdx.x, b = blockIdx.x;
    const int n = b >> 8;
    const int X0 = ((b >> 4) & 15) << 3;
    const int Y0 = (b & 15) << 3;
    const int lane = tid & 63, wv = tid >> 6;
    const int lx = lane & 15;
    const int q = lane >> 4;

    // prefetch spin for this thread's 4 output pixels (hides HBM latency under staging+K-loop)
    float sp[12];
#pragma unroll
    for (int r = 0; r < 4; ++r) {
        const int pl = (wv << 4) + (q << 2) + r;
        const int P = ((((n << 7) + X0 + (pl >> 3)) << 7) + Y0 + (pl & 7));
        sp[r * 3 + 0] = spin[3 * P + 0];
        sp[r * 3 + 1] = spin[3 * P + 1];
        sp[r * 3 + 2] = spin[3 * P + 2];
    }

    // stage weights: 50 chunks x 1024B, linear
    for (int j = 0; j < 13; ++j) {
        const int cid = j * 4 + wv;
        if (cid < 50)
            GLD16(ws + cid * 1024 + lane * 16, smem + cid * 1024);
    }
    // stage feat halo tile: 18 chunks x 1024B (8 px each), pre-swizzled source, linear dest
    const unsigned char* fsrc = ws + WBYTES;
    for (int j = 0; j < 5; ++j) {
        const int cid = wv + 4 * j;
        if (cid < 18) {
            const int px = cid * 8 + (lane >> 3);        // staged slot 0..143
            const int cc = lane & 7;
            const int dx = px / 12, dy = px - dx * 12;
            const int gx = (X0 - 2 + dx) & 127;
            const int gy = (Y0 - 2 + dy) & 127;
            GLD16(fsrc + (size_t)((((n << 7) + gx) << 7) + gy) * 128 + cc * 16,
                  smem + FLDS + cid * 1024);
        }
    }
    __syncthreads();

    const int u0b = (q & 1) << 4;
    const int taph = q >> 1;
    const int ploc = (wv << 4) + lx;
    const int slot0 = ((ploc >> 3) + 2) * 12 + ((ploc & 7) + 2);
    const char* flds = smem + FLDS;

    f32x4 aS0{0,0,0,0}, aS1{0,0,0,0};
    f32x4 aB0{0,0,0,0}, aB1{0,0,0,0}, aB2{0,0,0,0};
    f32x4 aC0{0,0,0,0}, aC1{0,0,0,0}, aC2{0,0,0,0};
    f32x4 aD0{0,0,0,0}, aD1{0,0,0,0}, aD2{0,0,0,0};

#pragma unroll
    for (int t = 0; t < 10; ++t) {
        const int tap = 2 * t + taph;
        const int st = slot0 + c_doff[tap];
        const char* ab = flds + st * 128;
        const int key = (st & 7) << 4;
        short8 a_s  = *(const short8*)(ab + ((u0b      ) ^ key));
        short8 a_v0 = *(const short8*)(ab + ((u0b + 32) ^ key));
        short8 a_v1 = *(const short8*)(ab + ((u0b + 64) ^ key));
        short8 a_v2 = *(const short8*)(ab + ((u0b + 96) ^ key));
        const char* bb = smem + tap * 512 + lx * 32 + u0b;
        short8 b000 = *(const short8*)(bb);
        short8 b011 = *(const short8*)(bb + 1 * 10240);
        short8 b101 = *(const short8*)(bb + 2 * 10240);
        short8 b110 = *(const short8*)(bb + 3 * 10240);
        short8 b111 = *(const short8*)(bb + 4 * 10240);
        aS0 = __builtin_amdgcn_mfma_f32_16x16x32_bf16(a_s,  b000, aS0, 0, 0, 0);
        aS1 = __builtin_amdgcn_mfma_f32_16x16x32_bf16(a_s,  b011, aS1, 0, 0, 0);
        aB0 = __builtin_amdgcn_mfma_f32_16x16x32_bf16(a_v0, b101, aB0, 0, 0, 0);
        aC0 = __builtin_amdgcn_mfma_f32_16x16x32_bf16(a_v0, b110, aC0, 0, 0, 0);
        aD0 = __builtin_amdgcn_mfma_f32_16x16x32_bf16(a_v0, b111, aD0, 0, 0, 0);
        aB1 = __builtin_amdgcn_mfma_f32_16x16x32_bf16(a_v1, b101, aB1, 0, 0, 0);
        aC1 = __builtin_amdgcn_mfma_f32_16x16x32_bf16(a_v1, b110, aC1, 0, 0, 0);
        aD1 = __builtin_amdgcn_mfma_f32_16x16x32_bf16(a_v1, b111, aD1, 0, 0, 0);
        aB2 = __builtin_amdgcn_mfma_f32_16x16x32_bf16(a_v2, b101, aB2, 0, 0, 0);
        aC2 = __builtin_amdgcn_mfma_f32_16x16x32_bf16(a_v2, b110, aC2, 0, 0, 0);
        aD2 = __builtin_amdgcn_mfma_f32_16x16x32_bf16(a_v2, b111, aD2, 0, 0, 0);
    }

    // epilogue: D row = pixel = q*4+r, col = w = lx
    const int w = lx;
#pragma unroll
    for (int r = 0; r < 4; ++r) {
        const int pl = (wv << 4) + (q << 2) + r;
        const int gx = X0 + (pl >> 3);
        const int gy = Y0 + (pl & 7);
        const int P = (((n << 7) + gx) << 7) + gy;
        const float s0 = C1F * sp[r * 3 + 1];   // sh1 = C1*spin[...,[1,2,0]]
        const float s1 = C1F * sp[r * 3 + 2];
        const float s2 = C1F * sp[r * 3 + 0];
        float* o = out + (size_t)P * 64;
        o[w] = ASC * (C0F * aS0[r] + IS3 * (s0 * aC0[r] + s1 * aC1[r] + s2 * aC2[r]));
        o[16 + 3 * w + 0] = AVC * (s0 * aS1[r] + C0F * aB0[r] + IS2 * (s2 * aD1[r] - s1 * aD2[r]));
        o[16 + 3 * w + 1] = AVC * (s1 * aS1[r] + C0F * aB1[r] + IS2 * (s0 * aD2[r] - s2 * aD0[r]));
        o[16 + 3 * w + 2] = AVC * (s2 * aS1[r] + C0F * aB2[r] + IS2 * (s1 * aD0[r] - s0 * aD1[r]));
    }
}

extern "C" void kernel_launch(void* const* d_in, const int* in_sizes, int n_in,
                              void* d_out, int out_size, void* d_ws, size_t ws_size,
                              hipStream_t stream) {
    const float* feat = (const float*)d_in[0];
    const float* spin = (const float*)d_in[1];
    const float* w000 = (const float*)d_in[2];
    const float* w011 = (const float*)d_in[3];
    const float* w101 = (const float*)d_in[4];
    const float* w110 = (const float*)d_in[5];
    const float* w111 = (const float*)d_in[6];
    float* out = (float*)d_out;
    unsigned char* ws = (unsigned char*)d_ws;   // [0,51200): bf16 weights; [51200, +8.39MB): bf16 feat

    static bool attr_set = false;
    if (!attr_set) {
        (void)hipFuncSetAttribute((const void*)spinconv_mfma,
                                  hipFuncAttributeMaxDynamicSharedMemorySize, LDS_TOTAL);
        attr_set = true;
    }

    hipLaunchKernelGGL(prep_kernel, dim3(2148), dim3(256), 0, stream,
                       feat, w000, w011, w101, w110, w111, ws);
    hipLaunchKernelGGL(spinconv_mfma, dim3(1024), dim3(256), LDS_TOTAL, stream,
                       ws, spin, out);
}

// Round 8
// 90.222 us; speedup vs baseline: 3.7455x; 1.0248x over previous
//
#include <hip/hip_runtime.h>

typedef __attribute__((ext_vector_type(8))) short short8;
typedef __attribute__((ext_vector_type(4))) float f32x4;
typedef __attribute__((ext_vector_type(4))) int i32x4;

#define C0F 0.28209479177387814f
#define C1F 0.4886025119029199f
#define IS3 0.5773502691896258f
#define IS2 0.7071067811865476f
#define ASC 0.040555354f   // 1/sqrt(2*19*16)
#define AVC 0.033113308f   // 1/sqrt(3*19*16)

#define WB 51200                 // weight bytes: 5 mats * 20 taps * 512 B (tap 19 = zeros), [m][tap][w16][u16]
#define FB 30720                 // feat tile: 240 slots * 128 B
#define LDS_TOTAL (WB + FB)      // 81920

// slot delta per tap, row stride 20 (8x16 tile + 2 halo each side => 12x20 slots); tap19 pad -> 0
__constant__ int c_doff[20] = {0, 21,20,-1,-21,-20,1,
                               42,41,40,19,-2,-22,-42,-41,-40,-19,2,22, 0};

__device__ inline unsigned short f32_bf16(float x) {
    unsigned int u = __float_as_uint(x);
    return (unsigned short)((u + 0x7FFF + ((u >> 16) & 1)) >> 16);
}

#define GLD16(gp, lp) __builtin_amdgcn_global_load_lds( \
    (const __attribute__((address_space(1))) unsigned int*)(gp), \
    (__attribute__((address_space(3))) unsigned int*)(lp), 16, 0, 0)

// ---- prepass: EXACT clone of the round-3 (passed) prep kernel ----
// blocks [0,2048): feat -> de-interleaved, chunk-swizzled bf16 (32 px/block)
// blocks [2048,2148): weights -> bf16 [m][tap20][w16][u16], tap19 = 0
__global__ __launch_bounds__(256) void prep_kernel(
    const float* __restrict__ feat,
    const float* __restrict__ w000, const float* __restrict__ w011,
    const float* __restrict__ w101, const float* __restrict__ w110,
    const float* __restrict__ w111, unsigned char* __restrict__ ws)
{
    const int t = threadIdx.x;
    if (blockIdx.x >= 2048) {
        int o = (blockIdx.x - 2048) * 256 + t;          // [0, 25600)
        int m = o / 5120;
        int r1 = o - m * 5120;
        int tap = r1 >> 8;                               // 0..19
        int r2 = r1 & 255;
        int w = r2 >> 4;
        int u = r2 & 15;
        const float* W = (m == 0) ? w000 : (m == 1) ? w011 : (m == 2) ? w101 : (m == 3) ? w110 : w111;
        float val = (tap < 19) ? W[tap * 256 + u * 16 + w] : 0.0f;
        ((unsigned short*)ws)[o] = f32_bf16(val);        // linear o == [m][tap][w][u16]
        return;
    }
    __shared__ float raw[2048];                          // 32 px * 64 ch
    const int P0 = blockIdx.x * 32;
    const float4* src = (const float4*)feat + (size_t)P0 * 16;
    float4 l0 = src[t * 2];
    float4 l1 = src[t * 2 + 1];
    *(float4*)&raw[t * 8] = l0;
    *(float4*)&raw[t * 8 + 4] = l1;
    __syncthreads();
    const int p = t >> 3;                                // local pixel
    const int c = t & 7;                                 // 16B chunk id
    const float* r = &raw[p * 64];
    int ch0, stride;
    if (c < 2) { ch0 = c * 8; stride = 1; }
    else { int i = (c - 2) >> 1, uh = (c - 2) & 1; ch0 = 16 + i + 24 * uh; stride = 3; }
    unsigned int pk[4];
#pragma unroll
    for (int e = 0; e < 4; ++e) {
        unsigned int lo = f32_bf16(r[ch0 + stride * (2 * e)]);
        unsigned int hi = f32_bf16(r[ch0 + stride * (2 * e + 1)]);
        pk[e] = lo | (hi << 16);
    }
    const int PX = P0 + p;
    const int gy = PX & 127, gx = (PX >> 7) & 127;
    const int k = (4 * gx + gy + 2) & 7;                 // == slot%8 for all tiles (origins % 8 == 0)
    *(i32x4*)(ws + WB + (size_t)PX * 128 + ((c ^ k) << 4)) = *(const i32x4*)pk;
}

// ---- main: 8x16 tile, 4 waves x 2 M-tiles (named accumulators), round-3 weight layout/addressing
__global__ __launch_bounds__(256) void spinconv_mfma(
    const unsigned char* __restrict__ ws, const float* __restrict__ spin,
    float* __restrict__ out)
{
    extern __shared__ char smem[];
    const int tid = threadIdx.x, b = blockIdx.x;
    const int n = b >> 7;
    const int X0 = ((b >> 3) & 15) << 3;   // 16 x-tiles of 8
    const int Y0 = (b & 7) << 4;           // 8 y-tiles of 16
    const int lane = tid & 63, wv = tid >> 6;
    const int lx = lane & 15;
    const int q = lane >> 4;

    // prefetch spin for this thread's 8 output pixels (2 M-tiles x 4 rows)
    float sp[24];
#pragma unroll
    for (int ti = 0; ti < 2; ++ti)
#pragma unroll
        for (int r = 0; r < 4; ++r) {
            const int x = X0 + 2 * wv + ti;
            const int y = Y0 + (q << 2) + r;
            const int P = (((n << 7) + x) << 7) + y;
            sp[ti * 12 + r * 3 + 0] = spin[3 * P + 0];
            sp[ti * 12 + r * 3 + 1] = spin[3 * P + 1];
            sp[ti * 12 + r * 3 + 2] = spin[3 * P + 2];
        }

    // stage weights: 50 full 1024B chunks (51200 B), wave-uniform predicates
    for (int j = 0; j < 13; ++j) {
        const int cid = j * 4 + wv;
        if (cid < 50)
            GLD16(ws + cid * 1024 + lane * 16, smem + cid * 1024);
    }
    // stage feat halo (12x20 slots = 30 chunks), pre-swizzled source, linear LDS dest
    const unsigned char* fsrc = ws + WB;
    for (int j = 0; j < 8; ++j) {
        const int cid = j * 4 + wv;
        if (cid < 30) {
            const int sl = cid * 8 + (lane >> 3);        // slot 0..239
            const int cc = lane & 7;
            const int dx = sl / 20, dy = sl - dx * 20;
            const int gx = (X0 - 2 + dx) & 127;
            const int gy = (Y0 - 2 + dy) & 127;
            GLD16(fsrc + (size_t)((((n << 7) + gx) << 7) + gy) * 128 + cc * 16,
                  smem + WB + cid * 1024);
        }
    }
    __syncthreads();

    const int u0b = (q & 1) << 4;          // byte offset of u-half
    const int taph = q >> 1;               // which tap of the K=32 pair
    const char* flds = smem + WB;
    const int s0a = (2 * wv + 2) * 20 + lx + 2;   // M-tile x-row 2wv, pixel y = Y0+lx
    const int s0b = s0a + 20;                     // M-tile x-row 2wv+1

    f32x4 aS0{0,0,0,0}, aS1{0,0,0,0}, aB0{0,0,0,0}, aB1{0,0,0,0}, aB2{0,0,0,0},
          aC0{0,0,0,0}, aC1{0,0,0,0}, aC2{0,0,0,0}, aD0{0,0,0,0}, aD1{0,0,0,0}, aD2{0,0,0,0};
    f32x4 bS0{0,0,0,0}, bS1{0,0,0,0}, bB0{0,0,0,0}, bB1{0,0,0,0}, bB2{0,0,0,0},
          bC0{0,0,0,0}, bC1{0,0,0,0}, bC2{0,0,0,0}, bD0{0,0,0,0}, bD1{0,0,0,0}, bD2{0,0,0,0};

#pragma unroll
    for (int t = 0; t < 10; ++t) {
        const int tap = 2 * t + taph;
        const int d = c_doff[tap];
        const int stA = s0a + d;
        const char* pa = flds + stA * 128;
        const int ka = (stA & 7) << 4;
        short8 xs  = *(const short8*)(pa + ((u0b      ) ^ ka));
        short8 x0  = *(const short8*)(pa + ((u0b + 32) ^ ka));
        short8 x1  = *(const short8*)(pa + ((u0b + 64) ^ ka));
        short8 x2  = *(const short8*)(pa + ((u0b + 96) ^ ka));
        const int stB = s0b + d;
        const char* pb = flds + stB * 128;
        const int kb = (stB & 7) << 4;
        short8 ys  = *(const short8*)(pb + ((u0b      ) ^ kb));
        short8 y0  = *(const short8*)(pb + ((u0b + 32) ^ kb));
        short8 y1  = *(const short8*)(pb + ((u0b + 64) ^ kb));
        short8 y2  = *(const short8*)(pb + ((u0b + 96) ^ kb));
        const char* bb = smem + tap * 512 + lx * 32 + u0b;   // round-3 [tap][w][u16] addressing
        short8 b000 = *(const short8*)(bb);
        short8 b011 = *(const short8*)(bb + 10240);
        short8 b101 = *(const short8*)(bb + 20480);
        short8 b110 = *(const short8*)(bb + 30720);
        short8 b111 = *(const short8*)(bb + 40960);
        aS0 = __builtin_amdgcn_mfma_f32_16x16x32_bf16(xs, b000, aS0, 0, 0, 0);
        aS1 = __builtin_amdgcn_mfma_f32_16x16x32_bf16(xs, b011, aS1, 0, 0, 0);
        aB0 = __builtin_amdgcn_mfma_f32_16x16x32_bf16(x0, b101, aB0, 0, 0, 0);
        aC0 = __builtin_amdgcn_mfma_f32_16x16x32_bf16(x0, b110, aC0, 0, 0, 0);
        aD0 = __builtin_amdgcn_mfma_f32_16x16x32_bf16(x0, b111, aD0, 0, 0, 0);
        aB1 = __builtin_amdgcn_mfma_f32_16x16x32_bf16(x1, b101, aB1, 0, 0, 0);
        aC1 = __builtin_amdgcn_mfma_f32_16x16x32_bf16(x1, b110, aC1, 0, 0, 0);
        aD1 = __builtin_amdgcn_mfma_f32_16x16x32_bf16(x1, b111, aD1, 0, 0, 0);
        aB2 = __builtin_amdgcn_mfma_f32_16x16x32_bf16(x2, b101, aB2, 0, 0, 0);
        aC2 = __builtin_amdgcn_mfma_f32_16x16x32_bf16(x2, b110, aC2, 0, 0, 0);
        aD2 = __builtin_amdgcn_mfma_f32_16x16x32_bf16(x2, b111, aD2, 0, 0, 0);
        bS0 = __builtin_amdgcn_mfma_f32_16x16x32_bf16(ys, b000, bS0, 0, 0, 0);
        bS1 = __builtin_amdgcn_mfma_f32_16x16x32_bf16(ys, b011, bS1, 0, 0, 0);
        bB0 = __builtin_amdgcn_mfma_f32_16x16x32_bf16(y0, b101, bB0, 0, 0, 0);
        bC0 = __builtin_amdgcn_mfma_f32_16x16x32_bf16(y0, b110, bC0, 0, 0, 0);
        bD0 = __builtin_amdgcn_mfma_f32_16x16x32_bf16(y0, b111, bD0, 0, 0, 0);
        bB1 = __builtin_amdgcn_mfma_f32_16x16x32_bf16(y1, b101, bB1, 0, 0, 0);
        bC1 = __builtin_amdgcn_mfma_f32_16x16x32_bf16(y1, b110, bC1, 0, 0, 0);
        bD1 = __builtin_amdgcn_mfma_f32_16x16x32_bf16(y1, b111, bD1, 0, 0, 0);
        bB2 = __builtin_amdgcn_mfma_f32_16x16x32_bf16(y2, b101, bB2, 0, 0, 0);
        bC2 = __builtin_amdgcn_mfma_f32_16x16x32_bf16(y2, b110, bC2, 0, 0, 0);
        bD2 = __builtin_amdgcn_mfma_f32_16x16x32_bf16(y2, b111, bD2, 0, 0, 0);
    }

    // epilogue: D row = q*4+r = y-offset, col = lx = w  (round-3 formulas, twice)
    const int w = lx;
#pragma unroll
    for (int r = 0; r < 4; ++r) {
        const int y = Y0 + (q << 2) + r;
        {
            const int x = X0 + 2 * wv;
            const int P = (((n << 7) + x) << 7) + y;
            const float s0 = C1F * sp[r * 3 + 1];
            const float s1 = C1F * sp[r * 3 + 2];
            const float s2 = C1F * sp[r * 3 + 0];
            float* o = out + (size_t)P * 64;
            o[w] = ASC * (C0F * aS0[r] + IS3 * (s0 * aC0[r] + s1 * aC1[r] + s2 * aC2[r]));
            o[16 + 3 * w + 0] = AVC * (s0 * aS1[r] + C0F * aB0[r] + IS2 * (s2 * aD1[r] - s1 * aD2[r]));
            o[16 + 3 * w + 1] = AVC * (s1 * aS1[r] + C0F * aB1[r] + IS2 * (s0 * aD2[r] - s2 * aD0[r]));
            o[16 + 3 * w + 2] = AVC * (s2 * aS1[r] + C0F * aB2[r] + IS2 * (s1 * aD0[r] - s0 * aD1[r]));
        }
        {
            const int x = X0 + 2 * wv + 1;
            const int P = (((n << 7) + x) << 7) + y;
            const float s0 = C1F * sp[12 + r * 3 + 1];
            const float s1 = C1F * sp[12 + r * 3 + 2];
            const float s2 = C1F * sp[12 + r * 3 + 0];
            float* o = out + (size_t)P * 64;
            o[w] = ASC * (C0F * bS0[r] + IS3 * (s0 * bC0[r] + s1 * bC1[r] + s2 * bC2[r]));
            o[16 + 3 * w + 0] = AVC * (s0 * bS1[r] + C0F * bB0[r] + IS2 * (s2 * bD1[r] - s1 * bD2[r]));
            o[16 + 3 * w + 1] = AVC * (s1 * bS1[r] + C0F * bB1[r] + IS2 * (s0 * bD2[r] - s2 * bD0[r]));
            o[16 + 3 * w + 2] = AVC * (s2 * bS1[r] + C0F * bB2[r] + IS2 * (s1 * bD0[r] - s0 * bD1[r]));
        }
    }
}

extern "C" void kernel_launch(void* const* d_in, const int* in_sizes, int n_in,
                              void* d_out, int out_size, void* d_ws, size_t ws_size,
                              hipStream_t stream) {
    const float* feat = (const float*)d_in[0];
    const float* spin = (const float*)d_in[1];
    const float* w000 = (const float*)d_in[2];
    const float* w011 = (const float*)d_in[3];
    const float* w101 = (const float*)d_in[4];
    const float* w110 = (const float*)d_in[5];
    const float* w111 = (const float*)d_in[6];
    float* out = (float*)d_out;
    unsigned char* ws = (unsigned char*)d_ws;   // [0,51200): bf16 weights; [51200, +8.39MB): bf16 feat

    static bool attr_set = false;
    if (!attr_set) {
        (void)hipFuncSetAttribute((const void*)spinconv_mfma,
                                  hipFuncAttributeMaxDynamicSharedMemorySize, LDS_TOTAL);
        attr_set = true;
    }

    hipLaunchKernelGGL(prep_kernel, dim3(2148), dim3(256), 0, stream,
                       feat, w000, w011, w101, w110, w111, ws);
    hipLaunchKernelGGL(spinconv_mfma, dim3(512), dim3(256), LDS_TOTAL, stream,
                       ws, spin, out);
}

// Round 9
// 88.723 us; speedup vs baseline: 3.8088x; 1.0169x over previous
//
#include <hip/hip_runtime.h>

typedef __attribute__((ext_vector_type(8))) short short8;
typedef __attribute__((ext_vector_type(4))) float f32x4;

#define C0F 0.28209479177387814f
#define C1F 0.4886025119029199f
#define IS3 0.5773502691896258f
#define IS2 0.7071067811865476f
#define ASC 0.040555354f   // 1/sqrt(2*19*16)
#define AVC 0.033113308f   // 1/sqrt(3*19*16)

#define WB 51200                 // weight bytes: 5 mats * 20 taps * 512 B (tap 19 = zeros), [m][tap][w16][u16]
#define FB 30720                 // feat tile: 240 slots * 128 B
#define LDS_TOTAL (WB + FB)      // 81920 -> exactly 2 blocks/CU

// slot delta per tap, row stride 20 (8x16 tile + 2 halo each side => 12x20 slots); tap19 pad -> 0
__constant__ int c_doff[20] = {0, 21,20,-1,-21,-20,1,
                               42,41,40,19,-2,-22,-42,-41,-40,-19,2,22, 0};

__device__ inline unsigned short f32_bf16(float x) {
    unsigned int u = __float_as_uint(x);
    return (unsigned short)((u + 0x7FFF + ((u >> 16) & 1)) >> 16);
}

#define GLD16(gp, lp) __builtin_amdgcn_global_load_lds( \
    (const __attribute__((address_space(1))) unsigned int*)(gp), \
    (__attribute__((address_space(3))) unsigned int*)(lp), 16, 0, 0)

// ---- weight prepass (tiny): weights -> bf16 [m][tap20][w16][u16], tap19 = 0
__global__ __launch_bounds__(256) void wprep_kernel(
    const float* __restrict__ w000, const float* __restrict__ w011,
    const float* __restrict__ w101, const float* __restrict__ w110,
    const float* __restrict__ w111, unsigned char* __restrict__ ws)
{
    int o = blockIdx.x * 256 + threadIdx.x;          // [0, 25600)
    int m = o / 5120;
    int r1 = o - m * 5120;
    int tap = r1 >> 8;                               // 0..19
    int r2 = r1 & 255;
    int w = r2 >> 4;
    int u = r2 & 15;
    const float* W = (m == 0) ? w000 : (m == 1) ? w011 : (m == 2) ? w101 : (m == 3) ? w110 : w111;
    float val = (tap < 19) ? W[tap * 256 + u * 16 + w] : 0.0f;
    ((unsigned short*)ws)[o] = f32_bf16(val);        // linear o == [m][tap][w][u16]
}

// ---- main: fused feat staging (f32 -> bf16 de-interleave in-kernel) + implicit-GEMM MFMA
__global__ __launch_bounds__(256) void spinconv_mfma(
    const float* __restrict__ feat, const unsigned char* __restrict__ wbf,
    const float* __restrict__ spin, float* __restrict__ out)
{
    extern __shared__ char smem[];
    const int tid = threadIdx.x, b = blockIdx.x;
    const int n = b >> 7;
    const int X0 = ((b >> 3) & 15) << 3;   // 16 x-tiles of 8
    const int Y0 = (b & 7) << 4;           // 8 y-tiles of 16
    const int lane = tid & 63, wv = tid >> 6;
    const int lx = lane & 15;
    const int q = lane >> 4;

    // prefetch spin for this thread's 8 output pixels (2 M-tiles x 4 rows)
    float sp[24];
#pragma unroll
    for (int ti = 0; ti < 2; ++ti)
#pragma unroll
        for (int r = 0; r < 4; ++r) {
            const int x = X0 + 2 * wv + ti;
            const int y = Y0 + (q << 2) + r;
            const int P = (((n << 7) + x) << 7) + y;
            sp[ti * 12 + r * 3 + 0] = spin[3 * P + 0];
            sp[ti * 12 + r * 3 + 1] = spin[3 * P + 1];
            sp[ti * 12 + r * 3 + 2] = spin[3 * P + 2];
        }

    // stage weights first (async DMA overlaps the feat convert below)
    for (int j = 0; j < 13; ++j) {
        const int cid = j * 4 + wv;
        if (cid < 50)
            GLD16(wbf + cid * 1024 + lane * 16, smem + cid * 1024);
    }

    // fused feat staging: 240 slots, 16 threads/slot, coalesced float4 reads,
    // f32->bf16 de-interleave, swizzled scalar LDS writes (key = slot & 7)
    const int j4 = tid & 15;
    int dch[4];
#pragma unroll
    for (int e = 0; e < 4; ++e) {
        const int ch = j4 * 4 + e;
        const int j = ch - 16;
        dch[e] = (ch < 16) ? ch : (16 + 16 * (j % 3) + j / 3);
    }
#pragma unroll
    for (int r = 0; r < 15; ++r) {
        const int sl = r * 16 + (tid >> 4);          // slot 0..239
        const int dx = sl / 20, dy = sl - dx * 20;
        const int gx = (X0 - 2 + dx) & 127;
        const int gy = (Y0 - 2 + dy) & 127;
        const float4 v = *((const float4*)(feat + (size_t)((((n << 7) + gx) << 7) + gy) * 64) + j4);
        char* base = smem + WB + sl * 128;
        const int key = sl & 7;
        const float vals[4] = {v.x, v.y, v.z, v.w};
#pragma unroll
        for (int e = 0; e < 4; ++e) {
            const int d = dch[e];
            *(unsigned short*)(base + (((d >> 3) ^ key) << 4) + (d & 7) * 2) = f32_bf16(vals[e]);
        }
    }
    __syncthreads();

    const int u0b = (q & 1) << 4;          // byte offset of u-half
    const int taph = q >> 1;               // which tap of the K=32 pair
    const char* flds = smem + WB;
    const int s0a = (2 * wv + 2) * 20 + lx + 2;   // M-tile x-row 2wv, pixel y = Y0+lx
    const int s0b = s0a + 20;                     // M-tile x-row 2wv+1

    f32x4 aS0{0,0,0,0}, aS1{0,0,0,0}, aB0{0,0,0,0}, aB1{0,0,0,0}, aB2{0,0,0,0},
          aC0{0,0,0,0}, aC1{0,0,0,0}, aC2{0,0,0,0}, aD0{0,0,0,0}, aD1{0,0,0,0}, aD2{0,0,0,0};
    f32x4 bS0{0,0,0,0}, bS1{0,0,0,0}, bB0{0,0,0,0}, bB1{0,0,0,0}, bB2{0,0,0,0},
          bC0{0,0,0,0}, bC1{0,0,0,0}, bC2{0,0,0,0}, bD0{0,0,0,0}, bD1{0,0,0,0}, bD2{0,0,0,0};

#pragma unroll
    for (int t = 0; t < 10; ++t) {
        const int tap = 2 * t + taph;
        const int d = c_doff[tap];
        const int stA = s0a + d;
        const char* pa = flds + stA * 128;
        const int ka = (stA & 7) << 4;
        short8 xs  = *(const short8*)(pa + ((u0b      ) ^ ka));
        short8 x0  = *(const short8*)(pa + ((u0b + 32) ^ ka));
        short8 x1  = *(const short8*)(pa + ((u0b + 64) ^ ka));
        short8 x2  = *(const short8*)(pa + ((u0b + 96) ^ ka));
        const int stB = s0b + d;
        const char* pb = flds + stB * 128;
        const int kb = (stB & 7) << 4;
        short8 ys  = *(const short8*)(pb + ((u0b      ) ^ kb));
        short8 y0  = *(const short8*)(pb + ((u0b + 32) ^ kb));
        short8 y1  = *(const short8*)(pb + ((u0b + 64) ^ kb));
        short8 y2  = *(const short8*)(pb + ((u0b + 96) ^ kb));
        const char* bb = smem + tap * 512 + lx * 32 + u0b;   // [tap][w][u16] addressing
        short8 b000 = *(const short8*)(bb);
        short8 b011 = *(const short8*)(bb + 10240);
        short8 b101 = *(const short8*)(bb + 20480);
        short8 b110 = *(const short8*)(bb + 30720);
        short8 b111 = *(const short8*)(bb + 40960);
        aS0 = __builtin_amdgcn_mfma_f32_16x16x32_bf16(xs, b000, aS0, 0, 0, 0);
        aS1 = __builtin_amdgcn_mfma_f32_16x16x32_bf16(xs, b011, aS1, 0, 0, 0);
        aB0 = __builtin_amdgcn_mfma_f32_16x16x32_bf16(x0, b101, aB0, 0, 0, 0);
        aC0 = __builtin_amdgcn_mfma_f32_16x16x32_bf16(x0, b110, aC0, 0, 0, 0);
        aD0 = __builtin_amdgcn_mfma_f32_16x16x32_bf16(x0, b111, aD0, 0, 0, 0);
        aB1 = __builtin_amdgcn_mfma_f32_16x16x32_bf16(x1, b101, aB1, 0, 0, 0);
        aC1 = __builtin_amdgcn_mfma_f32_16x16x32_bf16(x1, b110, aC1, 0, 0, 0);
        aD1 = __builtin_amdgcn_mfma_f32_16x16x32_bf16(x1, b111, aD1, 0, 0, 0);
        aB2 = __builtin_amdgcn_mfma_f32_16x16x32_bf16(x2, b101, aB2, 0, 0, 0);
        aC2 = __builtin_amdgcn_mfma_f32_16x16x32_bf16(x2, b110, aC2, 0, 0, 0);
        aD2 = __builtin_amdgcn_mfma_f32_16x16x32_bf16(x2, b111, aD2, 0, 0, 0);
        bS0 = __builtin_amdgcn_mfma_f32_16x16x32_bf16(ys, b000, bS0, 0, 0, 0);
        bS1 = __builtin_amdgcn_mfma_f32_16x16x32_bf16(ys, b011, bS1, 0, 0, 0);
        bB0 = __builtin_amdgcn_mfma_f32_16x16x32_bf16(y0, b101, bB0, 0, 0, 0);
        bC0 = __builtin_amdgcn_mfma_f32_16x16x32_bf16(y0, b110, bC0, 0, 0, 0);
        bD0 = __builtin_amdgcn_mfma_f32_16x16x32_bf16(y0, b111, bD0, 0, 0, 0);
        bB1 = __builtin_amdgcn_mfma_f32_16x16x32_bf16(y1, b101, bB1, 0, 0, 0);
        bC1 = __builtin_amdgcn_mfma_f32_16x16x32_bf16(y1, b110, bC1, 0, 0, 0);
        bD1 = __builtin_amdgcn_mfma_f32_16x16x32_bf16(y1, b111, bD1, 0, 0, 0);
        bB2 = __builtin_amdgcn_mfma_f32_16x16x32_bf16(y2, b101, bB2, 0, 0, 0);
        bC2 = __builtin_amdgcn_mfma_f32_16x16x32_bf16(y2, b110, bC2, 0, 0, 0);
        bD2 = __builtin_amdgcn_mfma_f32_16x16x32_bf16(y2, b111, bD2, 0, 0, 0);
    }

    // epilogue: D row = q*4+r = y-offset, col = lx = w
    const int w = lx;
#pragma unroll
    for (int r = 0; r < 4; ++r) {
        const int y = Y0 + (q << 2) + r;
        {
            const int x = X0 + 2 * wv;
            const int P = (((n << 7) + x) << 7) + y;
            const float s0 = C1F * sp[r * 3 + 1];
            const float s1 = C1F * sp[r * 3 + 2];
            const float s2 = C1F * sp[r * 3 + 0];
            float* o = out + (size_t)P * 64;
            o[w] = ASC * (C0F * aS0[r] + IS3 * (s0 * aC0[r] + s1 * aC1[r] + s2 * aC2[r]));
            o[16 + 3 * w + 0] = AVC * (s0 * aS1[r] + C0F * aB0[r] + IS2 * (s2 * aD1[r] - s1 * aD2[r]));
            o[16 + 3 * w + 1] = AVC * (s1 * aS1[r] + C0F * aB1[r] + IS2 * (s0 * aD2[r] - s2 * aD0[r]));
            o[16 + 3 * w + 2] = AVC * (s2 * aS1[r] + C0F * aB2[r] + IS2 * (s1 * aD0[r] - s0 * aD1[r]));
        }
        {
            const int x = X0 + 2 * wv + 1;
            const int P = (((n << 7) + x) << 7) + y;
            const float s0 = C1F * sp[12 + r * 3 + 1];
            const float s1 = C1F * sp[12 + r * 3 + 2];
            const float s2 = C1F * sp[12 + r * 3 + 0];
            float* o = out + (size_t)P * 64;
            o[w] = ASC * (C0F * bS0[r] + IS3 * (s0 * bC0[r] + s1 * bC1[r] + s2 * bC2[r]));
            o[16 + 3 * w + 0] = AVC * (s0 * bS1[r] + C0F * bB0[r] + IS2 * (s2 * bD1[r] - s1 * bD2[r]));
            o[16 + 3 * w + 1] = AVC * (s1 * bS1[r] + C0F * bB1[r] + IS2 * (s0 * bD2[r] - s2 * bD0[r]));
            o[16 + 3 * w + 2] = AVC * (s2 * bS1[r] + C0F * bB2[r] + IS2 * (s1 * bD0[r] - s0 * bD1[r]));
        }
    }
}

extern "C" void kernel_launch(void* const* d_in, const int* in_sizes, int n_in,
                              void* d_out, int out_size, void* d_ws, size_t ws_size,
                              hipStream_t stream) {
    const float* feat = (const float*)d_in[0];
    const float* spin = (const float*)d_in[1];
    const float* w000 = (const float*)d_in[2];
    const float* w011 = (const float*)d_in[3];
    const float* w101 = (const float*)d_in[4];
    const float* w110 = (const float*)d_in[5];
    const float* w111 = (const float*)d_in[6];
    float* out = (float*)d_out;
    unsigned char* ws = (unsigned char*)d_ws;   // [0,51200): bf16 weights

    static bool attr_set = false;
    if (!attr_set) {
        (void)hipFuncSetAttribute((const void*)spinconv_mfma,
                                  hipFuncAttributeMaxDynamicSharedMemorySize, LDS_TOTAL);
        attr_set = true;
    }

    hipLaunchKernelGGL(wprep_kernel, dim3(100), dim3(256), 0, stream,
                       w000, w011, w101, w110, w111, ws);
    hipLaunchKernelGGL(spinconv_mfma, dim3(512), dim3(256), LDS_TOTAL, stream,
                       feat, ws, spin, out);
}